// Round 6
// baseline (13572.888 us; speedup 1.0000x reference)
//
#include <hip/hip_runtime.h>

#define NPTS 16384
#define CH 128
#define KNN 9
#define NCAND 12
#define COUT 256

// Insert (d, idx) into an ascending (dist, idx)-lexicographic sorted top-N list.
template <int N>
__device__ __forceinline__ void insertN(float (&L)[N], int (&I)[N], float d, int idx) {
    bool pre = (d < L[N - 1]) || (d == L[N - 1] && idx < I[N - 1]);
    if (pre) {
        bool gt[N];
#pragma unroll
        for (int j = 0; j < N; ++j) gt[j] = (d < L[j]) || (d == L[j] && idx < I[j]);
#pragma unroll
        for (int j = N - 1; j >= 1; --j) {
            bool sh = gt[j - 1];
            L[j] = sh ? L[j - 1] : (gt[j] ? d : L[j]);
            I[j] = sh ? I[j - 1] : (gt[j] ? idx : I[j]);
        }
        if (gt[0]) { L[0] = d; I[0] = idx; }
    }
}

// ---------------- Kernel 1: numpy pairwise_sum replica of np.sum(x*x, -1) ----------------
// numpy loops.c.src base case (n=128 <= PW_BLOCKSIZE): products pre-rounded (separate
// multiply ufunc), then 8 scalar accumulators stride-8, 16 sequential adds each,
// combined ((r0+r1)+(r2+r3))+((r4+r5)+(r6+r7)). All via __fmul_rn/__fadd_rn.
__global__ __launch_bounds__(256) void sqnp_kernel(const float* __restrict__ x,
                                                   float* __restrict__ sq) {
    const int i = blockIdx.x * 256 + threadIdx.x;
    const float4* row4 = (const float4*)(x + (size_t)i * CH);
    float r[8];
    {
        float4 a = row4[0], b = row4[1];
        r[0] = __fmul_rn(a.x, a.x); r[1] = __fmul_rn(a.y, a.y);
        r[2] = __fmul_rn(a.z, a.z); r[3] = __fmul_rn(a.w, a.w);
        r[4] = __fmul_rn(b.x, b.x); r[5] = __fmul_rn(b.y, b.y);
        r[6] = __fmul_rn(b.z, b.z); r[7] = __fmul_rn(b.w, b.w);
    }
#pragma unroll
    for (int g = 1; g < 16; ++g) {
        float4 a = row4[2 * g], b = row4[2 * g + 1];
        r[0] = __fadd_rn(r[0], __fmul_rn(a.x, a.x));
        r[1] = __fadd_rn(r[1], __fmul_rn(a.y, a.y));
        r[2] = __fadd_rn(r[2], __fmul_rn(a.z, a.z));
        r[3] = __fadd_rn(r[3], __fmul_rn(a.w, a.w));
        r[4] = __fadd_rn(r[4], __fmul_rn(b.x, b.x));
        r[5] = __fadd_rn(r[5], __fmul_rn(b.y, b.y));
        r[6] = __fadd_rn(r[6], __fmul_rn(b.z, b.z));
        r[7] = __fadd_rn(r[7], __fmul_rn(b.w, b.w));
    }
    float t0 = __fadd_rn(__fadd_rn(r[0], r[1]), __fadd_rn(r[2], r[3]));
    float t1 = __fadd_rn(__fadd_rn(r[4], r[5]), __fadd_rn(r[6], r[7]));
    sq[i] = __fadd_rn(t0, t1);
}

// ---------------- Kernel 2: fused fp32 distance-GEMM + top-12 candidates ----------------
// Candidate generation only: 1e-4-scale arithmetic differences cannot eject the np
// top-9 from a top-12 (exact rank-9 -> rank-12 gap is ~3 distance units).
__global__ __launch_bounds__(256, 2) void knn_kernel(const float* __restrict__ x,
                                                     const float* __restrict__ sq,
                                                     int* __restrict__ cand) {
    __shared__ float Xq[64 * 128];
    __shared__ float Xc[2 * 64 * 64];
    const int t = threadIdx.x;
    const int txl = t >> 4;
    const int ty = t & 15;
    const int row0 = blockIdx.x * 64;
    const int qsw = (txl & 3) << 4;
    const int csw = ty << 2;

    {
        const float4* xg = (const float4*)(x + (size_t)row0 * CH);
#pragma unroll
        for (int it = 0; it < 8; ++it) {
            int fg = t + it * 256;
            int r = fg >> 5;
            int c4 = fg & 31;
            float4 v = xg[fg];
            *(float4*)&Xq[r * 128 + 4 * (c4 ^ ((r & 3) << 2))] = v;
        }
    }

    float sqr[4];
#pragma unroll
    for (int s = 0; s < 4; ++s) sqr[s] = sq[row0 + txl + 16 * s];

    float ld[4][NCAND];
    int li[4][NCAND];
#pragma unroll
    for (int s = 0; s < 4; ++s)
#pragma unroll
        for (int j = 0; j < NCAND; ++j) { ld[s][j] = __builtin_inff(); li[s][j] = 0x7fffffff; }

    const float* qp = Xq + txl * 128;
    const float* cp = Xc + ty * 64;

    for (int ct = 0; ct < NPTS; ct += 64) {
        const float4* xg = (const float4*)(x + (size_t)ct * CH);
#pragma unroll
        for (int it = 0; it < 8; ++it) {
            int fg = t + it * 256;
            int r = fg >> 5;
            int c4 = fg & 31;
            int h = c4 >> 4;
            int j = c4 & 15;
            float4 v = xg[fg];
            *(float4*)&Xc[h * 4096 + r * 64 + 4 * (j ^ (r & 15))] = v;
        }
        float sqc[4];
#pragma unroll
        for (int u = 0; u < 4; ++u) sqc[u] = sq[ct + ty + 16 * u];
        __syncthreads();

        float acc[4][4];
#pragma unroll
        for (int s = 0; s < 4; ++s)
#pragma unroll
            for (int u = 0; u < 4; ++u) acc[s][u] = 0.f;

#pragma unroll 4
        for (int k0 = 0; k0 < CH; k0 += 4) {
            float4 a[4], b[4];
            const int qo = k0 ^ qsw;
            const int co = ((k0 >> 6) * 4096) + ((k0 & 63) ^ csw);
#pragma unroll
            for (int s = 0; s < 4; ++s) a[s] = *(const float4*)(qp + s * 2048 + qo);
#pragma unroll
            for (int u = 0; u < 4; ++u) b[u] = *(const float4*)(cp + u * 1024 + co);
#pragma unroll
            for (int s = 0; s < 4; ++s)
#pragma unroll
                for (int u = 0; u < 4; ++u) {
                    acc[s][u] += a[s].x * b[u].x;
                    acc[s][u] += a[s].y * b[u].y;
                    acc[s][u] += a[s].z * b[u].z;
                    acc[s][u] += a[s].w * b[u].w;
                }
        }
        __syncthreads();

#pragma unroll
        for (int s = 0; s < 4; ++s) {
            const int rg = row0 + txl + 16 * s;
#pragma unroll
            for (int u = 0; u < 4; ++u) {
                const int cg = ct + ty + 16 * u;
                if (cg != rg) {
                    float d = sqr[s] + sqc[u] - 2.f * acc[s][u];
                    insertN<NCAND>(ld[s], li[s], d, cg);
                }
            }
        }
    }

#pragma unroll
    for (int s = 0; s < 4; ++s) {
#pragma unroll
        for (int st = 0; st < 4; ++st) {
            const int step = 1 << st;
            float od[NCAND];
            int oi[NCAND];
#pragma unroll
            for (int j = 0; j < NCAND; ++j) {
                od[j] = __shfl_xor(ld[s][j], step, 16);
                oi[j] = __shfl_xor(li[s][j], step, 16);
            }
#pragma unroll
            for (int j = 0; j < NCAND; ++j) insertN<NCAND>(ld[s], li[s], od[j], oi[j]);
        }
        if (ty == 0) {
            const int rg = row0 + txl + 16 * s;
#pragma unroll
            for (int j = 0; j < NCAND; ++j) cand[rg * NCAND + j] = li[s][j];
        }
    }
}

// ---------------- Kernel 2.5: numpy-fp32-replica re-rank of 12 candidates ----------------
// dot: BLAS sgemm per-element rounding = ONE accumulator, sequential ascending-k FMA.
// sq : numpy pairwise_sum replica (sqnp_kernel).
// d  : fl( fl(sq_i + sq_j) - fl(2*dot) )  -- numpy's elementwise combine.
// Select 9 smallest by (d, idx)-lex == stable argsort / top_k tie-break.
__global__ __launch_bounds__(256) void refine_np_kernel(const float* __restrict__ x,
                                                        const float* __restrict__ sq,
                                                        const int* __restrict__ cand,
                                                        int* __restrict__ nbr) {
    const int i = blockIdx.x * 256 + threadIdx.x;
    const float4* X4 = (const float4*)x;
    int ci[NCAND];
#pragma unroll
    for (int m = 0; m < NCAND; ++m) ci[m] = cand[i * NCAND + m];
    float dot[NCAND];
#pragma unroll
    for (int m = 0; m < NCAND; ++m) dot[m] = 0.f;
#pragma unroll 4
    for (int c4 = 0; c4 < 32; ++c4) {
        float4 xv = X4[(size_t)i * 32 + c4];
#pragma unroll
        for (int m = 0; m < NCAND; ++m) {
            float4 nv = X4[(size_t)ci[m] * 32 + c4];
            float a = dot[m];
            a = __builtin_fmaf(xv.x, nv.x, a);
            a = __builtin_fmaf(xv.y, nv.y, a);
            a = __builtin_fmaf(xv.z, nv.z, a);
            a = __builtin_fmaf(xv.w, nv.w, a);
            dot[m] = a;
        }
    }
    const float sqi = sq[i];
    float d[NCAND];
#pragma unroll
    for (int m = 0; m < NCAND; ++m) {
        float s = __fadd_rn(sqi, sq[ci[m]]);
        d[m] = __fsub_rn(s, __fmul_rn(2.0f, dot[m]));
    }

    unsigned used = 0;
#pragma unroll
    for (int s = 0; s < KNN; ++s) {
        float bd = __builtin_inff();
        int bi = 0x7fffffff, bm = 0;
#pragma unroll
        for (int m = 0; m < NCAND; ++m) {
            bool ok = !((used >> m) & 1);
            bool better = ok && ((d[m] < bd) || (d[m] == bd && ci[m] < bi));
            bd = better ? d[m] : bd;
            bi = better ? ci[m] : bi;
            bm = better ? m : bm;
        }
        used |= (1u << bm);
        nbr[i * KNN + s] = bi;
    }
}

// ---------------- Kernel 3: rel-pos add + max-relative + concat-GEMM ----------------
__global__ __launch_bounds__(256, 2) void out_kernel(const float* __restrict__ x,
                                                     const float* __restrict__ tab,
                                                     const float* __restrict__ W,
                                                     const float* __restrict__ bias,
                                                     const int* __restrict__ nbr,
                                                     float* __restrict__ out) {
    __shared__ float cat[32][260];
    const int t = threadIdx.x;
    const int row0 = blockIdx.x * 32;
    {
        const int row = t >> 3;
        const int q = t & 7;
        const int i = row0 + row;
        const int rel_i = (i >> 7) - (i & 127) + 127;
        int nb[KNN], reln[KNN];
#pragma unroll
        for (int j = 0; j < KNN; ++j) {
            nb[j] = nbr[i * KNN + j];
            reln[j] = (nb[j] >> 7) - (nb[j] & 127) + 127;
        }
        const float4* X4 = (const float4*)x;
        const float4* T4 = (const float4*)tab;
#pragma unroll
        for (int cc = 0; cc < 4; ++cc) {
            const int c4 = q * 4 + cc;
            float4 xv = X4[i * 32 + c4];
            float4 tv = T4[rel_i * 32 + c4];
            float4 xi;
            xi.x = xv.x + tv.x; xi.y = xv.y + tv.y; xi.z = xv.z + tv.z; xi.w = xv.w + tv.w;
            const float ninf = -__builtin_inff();
            float4 mx = {ninf, ninf, ninf, ninf};
#pragma unroll
            for (int j = 0; j < KNN; ++j) {
                float4 nv = X4[nb[j] * 32 + c4];
                float4 ntv = T4[reln[j] * 32 + c4];
                mx.x = fmaxf(mx.x, nv.x + ntv.x - xi.x);
                mx.y = fmaxf(mx.y, nv.y + ntv.y - xi.y);
                mx.z = fmaxf(mx.z, nv.z + ntv.z - xi.z);
                mx.w = fmaxf(mx.w, nv.w + ntv.w - xi.w);
            }
            *(float4*)&cat[row][c4 * 4] = xi;
            *(float4*)&cat[row][CH + c4 * 4] = mx;
        }
    }
    __syncthreads();

    float acc[32];
    const float bo = bias[t];
#pragma unroll
    for (int i = 0; i < 32; ++i) acc[i] = bo;
#pragma unroll 2
    for (int c0 = 0; c0 < 2 * CH; c0 += 4) {
        const float w0 = W[(c0 + 0) * COUT + t];
        const float w1 = W[(c0 + 1) * COUT + t];
        const float w2 = W[(c0 + 2) * COUT + t];
        const float w3 = W[(c0 + 3) * COUT + t];
#pragma unroll
        for (int i = 0; i < 32; ++i) {
            const float4 cv = *(const float4*)&cat[i][c0];
            acc[i] = fmaf(cv.x, w0, acc[i]);
            acc[i] = fmaf(cv.y, w1, acc[i]);
            acc[i] = fmaf(cv.z, w2, acc[i]);
            acc[i] = fmaf(cv.w, w3, acc[i]);
        }
    }
#pragma unroll
    for (int i = 0; i < 32; ++i) out[(size_t)(row0 + i) * COUT + t] = acc[i];
}

extern "C" void kernel_launch(void* const* d_in, const int* in_sizes, int n_in,
                              void* d_out, int out_size, void* d_ws, size_t ws_size,
                              hipStream_t stream) {
    (void)in_sizes; (void)n_in; (void)out_size; (void)ws_size;
    const float* x = (const float*)d_in[0];
    const float* tab = (const float*)d_in[1];
    const float* W = (const float*)d_in[2];
    const float* b = (const float*)d_in[3];
    float* out = (float*)d_out;

    char* ws = (char*)d_ws;
    float* sq = (float*)ws;                  // N floats
    int* cand = (int*)(sq + NPTS);           // N*12 ints
    int* nbr = cand + (size_t)NPTS * NCAND;  // N*9 ints

    sqnp_kernel<<<NPTS / 256, 256, 0, stream>>>(x, sq);
    knn_kernel<<<NPTS / 64, 256, 0, stream>>>(x, sq, cand);
    refine_np_kernel<<<NPTS / 256, 256, 0, stream>>>(x, sq, cand, nbr);
    out_kernel<<<NPTS / 32, 256, 0, stream>>>(x, tab, W, b, nbr, out);
}